// Round 1
// baseline (319.813 us; speedup 1.0000x reference)
//
#include <hip/hip_runtime.h>

// Problem: B=2,S=2048,H=1024,NH=16,HD=64 fused attention block.
// Round 1: correctness-first full-MFMA pipeline.
#define B_  2
#define S_  2048
#define H_  1024
#define NH_ 16
#define HD_ 64
#define M_  (B_*S_)   // 4096 rows

typedef __attribute__((ext_vector_type(8))) __bf16 bf16x8;
typedef __attribute__((ext_vector_type(4))) float  f32x4;
typedef __attribute__((ext_vector_type(8))) unsigned short us8;
typedef __attribute__((ext_vector_type(4))) float  fl4;

__device__ __forceinline__ unsigned short f2bf(float f) {
    unsigned int u = __float_as_uint(f);
    u += 0x7fffu + ((u >> 16) & 1u);          // round-to-nearest-even
    return (unsigned short)(u >> 16);
}

// ---------------- cast fp32 -> bf16 (x and the 4 weights) ----------------
__global__ __launch_bounds__(256) void cast_kernel(
    const float* __restrict__ x,
    const float* __restrict__ wq, const float* __restrict__ wk,
    const float* __restrict__ wv, const float* __restrict__ wo,
    unsigned short* __restrict__ xb, unsigned short* __restrict__ wb) {
    size_t t  = (size_t)blockIdx.x * 256 + threadIdx.x;
    size_t e0 = t * 4;
    const size_t XN = (size_t)M_ * H_;        // 4M
    const float* src;
    unsigned short* dst;
    if (e0 < XN) { src = x + e0; dst = xb + e0; }
    else {
        size_t j = e0 - XN;                    // 0..4M over 4 weights of 1M
        int w = (int)(j >> 20);
        size_t off = j & ((1u << 20) - 1);
        const float* wp = (w == 0) ? wq : (w == 1) ? wk : (w == 2) ? wv : wo;
        src = wp + off; dst = wb + j;
    }
    fl4 v = *(const fl4*)src;
    ushort4 o;
    o.x = f2bf(v.x); o.y = f2bf(v.y); o.z = f2bf(v.z); o.w = f2bf(v.w);
    *(ushort4*)dst = o;
}

// ---------------- QKV GEMM: out = x @ W^T + bias (bf16 out) ----------------
// C[m,n] = sum_k A[m,k] * W[n,k]  (both row-major along k -> "B^T" gemm)
__global__ __launch_bounds__(256) void gemm_qkv(
    const unsigned short* __restrict__ xb, const unsigned short* __restrict__ wb,
    const float* __restrict__ bq, const float* __restrict__ bk,
    const float* __restrict__ bv, unsigned short* __restrict__ outb) {
    __shared__ __align__(16) unsigned short As[64 * 72];
    __shared__ __align__(16) unsigned short Ws[64 * 72];
    const int z = blockIdx.z;
    const unsigned short* W = wb + (size_t)z * H_ * H_;
    const float* bias = (z == 0) ? bq : (z == 1) ? bk : bv;
    unsigned short* out = outb + (size_t)z * M_ * H_;
    const int m0 = blockIdx.x * 64, n0 = blockIdx.y * 64;
    const int t = threadIdx.x;
    const int lane = t & 63, wid = t >> 6, quad = lane >> 4, l16 = lane & 15;
    const int sr = t >> 2, sc = (t & 3) * 16;

    f32x4 acc[4] = {};
    for (int k0 = 0; k0 < H_; k0 += 64) {
        const us8* ga = (const us8*)(xb + (size_t)(m0 + sr) * H_ + k0 + sc);
        const us8* gw = (const us8*)(W  + (size_t)(n0 + sr) * H_ + k0 + sc);
        us8 a0 = ga[0], a1 = ga[1], w0 = gw[0], w1 = gw[1];
        *(us8*)&As[sr * 72 + sc]     = a0;  *(us8*)&As[sr * 72 + sc + 8] = a1;
        *(us8*)&Ws[sr * 72 + sc]     = w0;  *(us8*)&Ws[sr * 72 + sc + 8] = w1;
        __syncthreads();
#pragma unroll
        for (int kk = 0; kk < 64; kk += 32) {
            bf16x8 af = *(const bf16x8*)&As[(wid * 16 + l16) * 72 + kk + quad * 8];
#pragma unroll
            for (int nt = 0; nt < 4; nt++) {
                bf16x8 bf = *(const bf16x8*)&Ws[(nt * 16 + l16) * 72 + kk + quad * 8];
                acc[nt] = __builtin_amdgcn_mfma_f32_16x16x32_bf16(af, bf, acc[nt], 0, 0, 0);
            }
        }
        __syncthreads();
    }
#pragma unroll
    for (int nt = 0; nt < 4; nt++) {
        int col = n0 + nt * 16 + l16;
        float bval = bias[col];
#pragma unroll
        for (int r = 0; r < 4; r++) {
            int row = m0 + wid * 16 + quad * 4 + r;
            out[(size_t)row * H_ + col] = f2bf(acc[nt][r] + bval);
        }
    }
}

// ---------------- Wo GEMM + bias + residual (fp32 out to ws) ----------------
__global__ __launch_bounds__(256) void gemm_out(
    const unsigned short* __restrict__ ctxb, const unsigned short* __restrict__ wob,
    const float* __restrict__ bo, const float* __restrict__ x,
    float* __restrict__ y) {
    __shared__ __align__(16) unsigned short As[64 * 72];
    __shared__ __align__(16) unsigned short Ws[64 * 72];
    const int m0 = blockIdx.x * 64, n0 = blockIdx.y * 64;
    const int t = threadIdx.x;
    const int lane = t & 63, wid = t >> 6, quad = lane >> 4, l16 = lane & 15;
    const int sr = t >> 2, sc = (t & 3) * 16;

    f32x4 acc[4] = {};
    for (int k0 = 0; k0 < H_; k0 += 64) {
        const us8* ga = (const us8*)(ctxb + (size_t)(m0 + sr) * H_ + k0 + sc);
        const us8* gw = (const us8*)(wob  + (size_t)(n0 + sr) * H_ + k0 + sc);
        us8 a0 = ga[0], a1 = ga[1], w0 = gw[0], w1 = gw[1];
        *(us8*)&As[sr * 72 + sc]     = a0;  *(us8*)&As[sr * 72 + sc + 8] = a1;
        *(us8*)&Ws[sr * 72 + sc]     = w0;  *(us8*)&Ws[sr * 72 + sc + 8] = w1;
        __syncthreads();
#pragma unroll
        for (int kk = 0; kk < 64; kk += 32) {
            bf16x8 af = *(const bf16x8*)&As[(wid * 16 + l16) * 72 + kk + quad * 8];
#pragma unroll
            for (int nt = 0; nt < 4; nt++) {
                bf16x8 bf = *(const bf16x8*)&Ws[(nt * 16 + l16) * 72 + kk + quad * 8];
                acc[nt] = __builtin_amdgcn_mfma_f32_16x16x32_bf16(af, bf, acc[nt], 0, 0, 0);
            }
        }
        __syncthreads();
    }
#pragma unroll
    for (int nt = 0; nt < 4; nt++) {
        int col = n0 + nt * 16 + l16;
        float bval = bo[col];
#pragma unroll
        for (int r = 0; r < 4; r++) {
            size_t idx = (size_t)(m0 + wid * 16 + quad * 4 + r) * H_ + col;
            y[idx] = acc[nt][r] + bval + x[idx];
        }
    }
}

// ---------------- Flash attention (causal), 1 wg per (b,h,64-q-tile) --------
__global__ __launch_bounds__(256) void attn_kernel(
    const unsigned short* __restrict__ qb, const unsigned short* __restrict__ kb,
    const unsigned short* __restrict__ vb, unsigned short* __restrict__ ctxb) {
    __shared__ __align__(16) unsigned short Ks[64 * 72];
    __shared__ __align__(16) unsigned short Vt[64 * 72];   // V^T: [d][key]
    __shared__ __align__(16) unsigned short Ps[64 * 72];   // per-wave 16-row chunks
    const int b = blockIdx.z, h = blockIdx.y, q0 = blockIdx.x * 64;
    const int t = threadIdx.x, lane = t & 63, wid = t >> 6;
    const int quad = lane >> 4, l16 = lane & 15;
    const int sr = t >> 2, sc = (t & 3) * 16;
    const size_t headoff = (size_t)h * HD_;

    // Q fragments for this wave's 16 rows (fixed across k-steps)
    const size_t qrow = (size_t)(b * S_ + q0 + wid * 16 + l16);
    bf16x8 qf0 = *(const bf16x8*)(qb + qrow * H_ + headoff + quad * 8);
    bf16x8 qf1 = *(const bf16x8*)(qb + qrow * H_ + headoff + 32 + quad * 8);

    float m_r[4], l_r[4];
    f32x4 o_acc[4] = {};
#pragma unroll
    for (int r = 0; r < 4; r++) { m_r[r] = -INFINITY; l_r[r] = 0.f; }

    const int nsteps = blockIdx.x + 1;       // causal: tiles k0 <= q0
    for (int s = 0; s < nsteps; s++) {
        const int k0 = s * 64;
        // stage K tile (row-major) and V tile (transposed)
        const us8* gk = (const us8*)(kb + (size_t)(b * S_ + k0 + sr) * H_ + headoff + sc);
        const us8* gv = (const us8*)(vb + (size_t)(b * S_ + k0 + sr) * H_ + headoff + sc);
        us8 kv0 = gk[0], kv1 = gk[1];
        us8 vv0 = gv[0], vv1 = gv[1];
        *(us8*)&Ks[sr * 72 + sc]     = kv0;  *(us8*)&Ks[sr * 72 + sc + 8] = kv1;
#pragma unroll
        for (int j = 0; j < 8; j++) Vt[(sc + j) * 72 + sr]     = vv0[j];
#pragma unroll
        for (int j = 0; j < 8; j++) Vt[(sc + 8 + j) * 72 + sr] = vv1[j];
        __syncthreads();

        // S = Q K^T  (16x64 per wave)
        f32x4 sacc[4] = {};
#pragma unroll
        for (int kk = 0; kk < 64; kk += 32) {
            bf16x8 af = (kk == 0) ? qf0 : qf1;
#pragma unroll
            for (int nt = 0; nt < 4; nt++) {
                bf16x8 bf = *(const bf16x8*)&Ks[(nt * 16 + l16) * 72 + kk + quad * 8];
                sacc[nt] = __builtin_amdgcn_mfma_f32_16x16x32_bf16(af, bf, sacc[nt], 0, 0, 0);
            }
        }
        // scale + causal mask (only the k0==q0 tile is partial)
        const bool diag = (k0 == q0);
        float sv[4][4];
#pragma unroll
        for (int nt = 0; nt < 4; nt++) {
            int n = nt * 16 + l16;           // key within 64-tile
#pragma unroll
            for (int r = 0; r < 4; r++) {
                float v = sacc[nt][r] * 0.125f;   // 1/sqrt(64)
                int qidx = wid * 16 + quad * 4 + r; // query within 64-block
                if (diag && n > qidx) v = -1e30f;
                sv[nt][r] = v;
            }
        }
        // online softmax, rows live across 16-lane groups
#pragma unroll
        for (int r = 0; r < 4; r++) {
            float mx = fmaxf(fmaxf(sv[0][r], sv[1][r]), fmaxf(sv[2][r], sv[3][r]));
            mx = fmaxf(mx, __shfl_xor(mx, 1));
            mx = fmaxf(mx, __shfl_xor(mx, 2));
            mx = fmaxf(mx, __shfl_xor(mx, 4));
            mx = fmaxf(mx, __shfl_xor(mx, 8));
            float m_new = fmaxf(m_r[r], mx);
            float alpha = __expf(m_r[r] - m_new);
            float ssum = 0.f;
#pragma unroll
            for (int nt = 0; nt < 4; nt++) {
                float p = __expf(sv[nt][r] - m_new);
                sv[nt][r] = p;
                ssum += p;
            }
            ssum += __shfl_xor(ssum, 1);
            ssum += __shfl_xor(ssum, 2);
            ssum += __shfl_xor(ssum, 4);
            ssum += __shfl_xor(ssum, 8);
            l_r[r] = l_r[r] * alpha + ssum;
            m_r[r] = m_new;
#pragma unroll
            for (int dt = 0; dt < 4; dt++) o_acc[dt][r] *= alpha;
        }
        // P: C-layout -> A-layout via LDS (per-wave private rows)
#pragma unroll
        for (int nt = 0; nt < 4; nt++)
#pragma unroll
            for (int r = 0; r < 4; r++)
                Ps[(wid * 16 + quad * 4 + r) * 72 + nt * 16 + l16] = f2bf(sv[nt][r]);
        __threadfence_block();   // order LDS writes before cross-lane reads (same wave)
        // O += P V
#pragma unroll
        for (int kk = 0; kk < 64; kk += 32) {
            bf16x8 pf = *(const bf16x8*)&Ps[(wid * 16 + l16) * 72 + kk + quad * 8];
#pragma unroll
            for (int dt = 0; dt < 4; dt++) {
                bf16x8 vf = *(const bf16x8*)&Vt[(dt * 16 + l16) * 72 + kk + quad * 8];
                o_acc[dt] = __builtin_amdgcn_mfma_f32_16x16x32_bf16(pf, vf, o_acc[dt], 0, 0, 0);
            }
        }
        __syncthreads();
    }
    // normalize + store ctx (bf16, [B*S, H] with head offset)
#pragma unroll
    for (int r = 0; r < 4; r++) {
        float inv = 1.0f / l_r[r];
        size_t row = (size_t)(b * S_ + q0 + wid * 16 + quad * 4 + r);
#pragma unroll
        for (int dt = 0; dt < 4; dt++)
            ctxb[row * H_ + headoff + dt * 16 + l16] = f2bf(o_acc[dt][r] * inv);
    }
}

// ---------------- LayerNorm (1 block per row) ----------------
__global__ __launch_bounds__(256) void ln_kernel(
    const float* __restrict__ y, const float* __restrict__ g,
    const float* __restrict__ bta, float* __restrict__ out) {
    __shared__ float red[8];
    const int row = blockIdx.x, t = threadIdx.x;
    fl4 v = *(const fl4*)(y + (size_t)row * H_ + t * 4);
    float s  = v.x + v.y + v.z + v.w;
    float sq = v.x * v.x + v.y * v.y + v.z * v.z + v.w * v.w;
    for (int m = 1; m < 64; m <<= 1) { s += __shfl_xor(s, m); sq += __shfl_xor(sq, m); }
    const int wid = t >> 6, lane = t & 63;
    if (lane == 0) { red[wid * 2] = s; red[wid * 2 + 1] = sq; }
    __syncthreads();
    s  = red[0] + red[2] + red[4] + red[6];
    sq = red[1] + red[3] + red[5] + red[7];
    float mu   = s * (1.0f / H_);
    float var  = sq * (1.0f / H_) - mu * mu;
    float rstd = rsqrtf(fmaxf(var, 0.f) + 1e-12f);
    fl4 gg = *(const fl4*)(g + t * 4);
    fl4 bb = *(const fl4*)(bta + t * 4);
    fl4 o;
    o.x = (v.x - mu) * rstd * gg.x + bb.x;
    o.y = (v.y - mu) * rstd * gg.y + bb.y;
    o.z = (v.z - mu) * rstd * gg.z + bb.z;
    o.w = (v.w - mu) * rstd * gg.w + bb.w;
    *(fl4*)(out + (size_t)row * H_ + t * 4) = o;
}

extern "C" void kernel_launch(void* const* d_in, const int* in_sizes, int n_in,
                              void* d_out, int out_size, void* d_ws, size_t ws_size,
                              hipStream_t stream) {
    const float* x  = (const float*)d_in[0];
    const float* Wq = (const float*)d_in[1];
    const float* bq = (const float*)d_in[2];
    const float* Wk = (const float*)d_in[3];
    const float* bk = (const float*)d_in[4];
    const float* Wv = (const float*)d_in[5];
    const float* bv = (const float*)d_in[6];
    const float* Wo = (const float*)d_in[7];
    const float* bo = (const float*)d_in[8];
    const float* lg = (const float*)d_in[9];
    const float* lb = (const float*)d_in[10];
    float* out = (float*)d_out;

    const size_t MEG = 1024u * 1024u;
    unsigned short* ws16 = (unsigned short*)d_ws;
    unsigned short* xb   = ws16;                  // 4M bf16
    unsigned short* wb   = ws16 + 4 * MEG;        // 4x1M bf16 (Wq,Wk,Wv,Wo)
    unsigned short* qb   = ws16 + 8 * MEG;        // 4M bf16
    unsigned short* kb   = ws16 + 12 * MEG;
    unsigned short* vb   = ws16 + 16 * MEG;
    unsigned short* ctxb = ws16 + 20 * MEG;
    float* y = (float*)(ws16 + 24 * MEG);         // 4M fp32 (16 MB); total 64 MB

    cast_kernel<<<8192, 256, 0, stream>>>(x, Wq, Wk, Wv, Wo, xb, wb);
    gemm_qkv<<<dim3(64, 16, 3), 256, 0, stream>>>(xb, wb, bq, bk, bv, qb);
    attn_kernel<<<dim3(32, 16, 2), 256, 0, stream>>>(qb, kb, vb, ctxb);
    gemm_out<<<dim3(64, 16), 256, 0, stream>>>(ctxb, wb + 3 * MEG, bo, x, y);
    ln_kernel<<<4096, 256, 0, stream>>>(y, lg, lb, out);
}

// Round 2
// 250.961 us; speedup vs baseline: 1.2744x; 1.2744x over previous
//
#include <hip/hip_runtime.h>

// B=2,S=2048,H=1024,NH=16,HD=64 fused attention block.
// Round 2: balanced paired-tile flash attention + pre-transposed V +
//          m97-style 128x128 global_load_lds GEMMs.
#define B_  2
#define S_  2048
#define H_  1024
#define NH_ 16
#define HD_ 64
#define M_  (B_*S_)   // 4096 rows

typedef __attribute__((ext_vector_type(8))) __bf16 bf16x8;
typedef __attribute__((ext_vector_type(4))) float  f32x4;
typedef __attribute__((ext_vector_type(8))) unsigned short us8;
typedef __attribute__((ext_vector_type(4))) float  fl4;

#define GL16(g, l) __builtin_amdgcn_global_load_lds( \
    (const __attribute__((address_space(1))) unsigned int*)(g), \
    (__attribute__((address_space(3))) unsigned int*)(l), 16, 0, 0)

__device__ __forceinline__ unsigned short f2bf(float f) {
    unsigned int u = __float_as_uint(f);
    u += 0x7fffu + ((u >> 16) & 1u);          // round-to-nearest-even
    return (unsigned short)(u >> 16);
}

// ---------------- cast fp32 -> bf16 (x and the 4 weights) ----------------
__global__ __launch_bounds__(256) void cast_kernel(
    const float* __restrict__ x,
    const float* __restrict__ wq, const float* __restrict__ wk,
    const float* __restrict__ wv, const float* __restrict__ wo,
    unsigned short* __restrict__ xb, unsigned short* __restrict__ wb) {
    size_t t  = (size_t)blockIdx.x * 256 + threadIdx.x;
    size_t e0 = t * 4;
    const size_t XN = (size_t)M_ * H_;        // 4M
    const float* src;
    unsigned short* dst;
    if (e0 < XN) { src = x + e0; dst = xb + e0; }
    else {
        size_t j = e0 - XN;                    // 0..4M over 4 weights of 1M
        int w = (int)(j >> 20);
        size_t off = j & ((1u << 20) - 1);
        const float* wp = (w == 0) ? wq : (w == 1) ? wk : (w == 2) ? wv : wo;
        src = wp + off; dst = wb + j;
    }
    fl4 v = *(const fl4*)src;
    ushort4 o;
    o.x = f2bf(v.x); o.y = f2bf(v.y); o.z = f2bf(v.z); o.w = f2bf(v.w);
    *(ushort4*)dst = o;
}

// ---------------- QKV GEMM (128x128 tile, global_load_lds) ----------------
// C[m,n] = sum_k x[m,k] * W[n,k] + bias[n]
// z==0 -> Q row-major bf16; z==1 -> K row-major bf16; z==2 -> V transposed
// vT[((b*NH+h)*HD+d)*S + s]
__global__ __launch_bounds__(256) void gemm_qkv(
    const unsigned short* __restrict__ xb, const unsigned short* __restrict__ wb,
    const float* __restrict__ bq, const float* __restrict__ bk,
    const float* __restrict__ bv,
    unsigned short* __restrict__ qb, unsigned short* __restrict__ kbuf,
    unsigned short* __restrict__ vT) {
    __shared__ __align__(16) unsigned short As[128 * 64];
    __shared__ __align__(16) unsigned short Bs[128 * 64];
    const int z = blockIdx.z;
    const unsigned short* W = wb + ((size_t)z << 20);
    const int m0 = blockIdx.x * 128, n0 = blockIdx.y * 128;
    const int t = threadIdx.x, lane = t & 63, w = t >> 6;
    const int wm = w >> 1, wn = w & 1, quad = lane >> 4, l16 = lane & 15;
    // staging: wave w covers rows w*32..w*32+31; lane l -> row l>>3, col (l&7)*8
    const int srow = w * 32 + (lane >> 3);
    const int scol = (lane & 7) * 8;
    const unsigned short* ga = xb + (size_t)(m0 + srow) * H_ + scol;
    const unsigned short* gb = W  + (size_t)(n0 + srow) * H_ + scol;

    f32x4 acc[4][4] = {};
    for (int k0 = 0; k0 < H_; k0 += 64) {
        __syncthreads();
#pragma unroll
        for (int j = 0; j < 4; j++) {
            GL16(ga + (size_t)(j * 8) * H_ + k0, &As[(w * 32 + j * 8) * 64]);
            GL16(gb + (size_t)(j * 8) * H_ + k0, &Bs[(w * 32 + j * 8) * 64]);
        }
        __syncthreads();
#pragma unroll
        for (int kk = 0; kk < 64; kk += 32) {
            bf16x8 af[4], bfr[4];
#pragma unroll
            for (int i = 0; i < 4; i++)
                af[i]  = *(const bf16x8*)&As[(wm * 64 + i * 16 + l16) * 64 + kk + quad * 8];
#pragma unroll
            for (int i = 0; i < 4; i++)
                bfr[i] = *(const bf16x8*)&Bs[(wn * 64 + i * 16 + l16) * 64 + kk + quad * 8];
#pragma unroll
            for (int mi = 0; mi < 4; mi++)
#pragma unroll
                for (int ni = 0; ni < 4; ni++)
                    acc[mi][ni] = __builtin_amdgcn_mfma_f32_16x16x32_bf16(
                        af[mi], bfr[ni], acc[mi][ni], 0, 0, 0);
        }
    }
    const float* bias = (z == 0) ? bq : (z == 1) ? bk : bv;
    if (z == 2) {
        // transposed V store: 4 consecutive s per lane -> ushort4
#pragma unroll
        for (int mi = 0; mi < 4; mi++) {
#pragma unroll
            for (int ni = 0; ni < 4; ni++) {
                int col  = n0 + wn * 64 + ni * 16 + l16;   // h*64+d
                float bval = bias[col];
                int row0 = m0 + wm * 64 + mi * 16 + quad * 4;  // b*2048+s
                int bb = row0 >> 11, s0 = row0 & 2047;
                ushort4 pk;
                pk.x = f2bf(acc[mi][ni][0] + bval);
                pk.y = f2bf(acc[mi][ni][1] + bval);
                pk.z = f2bf(acc[mi][ni][2] + bval);
                pk.w = f2bf(acc[mi][ni][3] + bval);
                *(ushort4*)&vT[((size_t)bb * NH_ * HD_ + col) * S_ + s0] = pk;
            }
        }
    } else {
        unsigned short* out = (z == 0) ? qb : kbuf;
#pragma unroll
        for (int mi = 0; mi < 4; mi++) {
#pragma unroll
            for (int ni = 0; ni < 4; ni++) {
                int col = n0 + wn * 64 + ni * 16 + l16;
                float bval = bias[col];
#pragma unroll
                for (int r = 0; r < 4; r++) {
                    int row = m0 + wm * 64 + mi * 16 + quad * 4 + r;
                    out[(size_t)row * H_ + col] = f2bf(acc[mi][ni][r] + bval);
                }
            }
        }
    }
}

// ---------------- Wo GEMM + bias + residual (128x128, fp32 out) ------------
__global__ __launch_bounds__(256) void gemm_out(
    const unsigned short* __restrict__ ctxb, const unsigned short* __restrict__ wob,
    const float* __restrict__ bo, const float* __restrict__ x,
    float* __restrict__ y) {
    __shared__ __align__(16) unsigned short As[128 * 64];
    __shared__ __align__(16) unsigned short Bs[128 * 64];
    const int m0 = blockIdx.x * 128, n0 = blockIdx.y * 128;
    const int t = threadIdx.x, lane = t & 63, w = t >> 6;
    const int wm = w >> 1, wn = w & 1, quad = lane >> 4, l16 = lane & 15;
    const int srow = w * 32 + (lane >> 3);
    const int scol = (lane & 7) * 8;
    const unsigned short* ga = ctxb + (size_t)(m0 + srow) * H_ + scol;
    const unsigned short* gb = wob  + (size_t)(n0 + srow) * H_ + scol;

    f32x4 acc[4][4] = {};
    for (int k0 = 0; k0 < H_; k0 += 64) {
        __syncthreads();
#pragma unroll
        for (int j = 0; j < 4; j++) {
            GL16(ga + (size_t)(j * 8) * H_ + k0, &As[(w * 32 + j * 8) * 64]);
            GL16(gb + (size_t)(j * 8) * H_ + k0, &Bs[(w * 32 + j * 8) * 64]);
        }
        __syncthreads();
#pragma unroll
        for (int kk = 0; kk < 64; kk += 32) {
            bf16x8 af[4], bfr[4];
#pragma unroll
            for (int i = 0; i < 4; i++)
                af[i]  = *(const bf16x8*)&As[(wm * 64 + i * 16 + l16) * 64 + kk + quad * 8];
#pragma unroll
            for (int i = 0; i < 4; i++)
                bfr[i] = *(const bf16x8*)&Bs[(wn * 64 + i * 16 + l16) * 64 + kk + quad * 8];
#pragma unroll
            for (int mi = 0; mi < 4; mi++)
#pragma unroll
                for (int ni = 0; ni < 4; ni++)
                    acc[mi][ni] = __builtin_amdgcn_mfma_f32_16x16x32_bf16(
                        af[mi], bfr[ni], acc[mi][ni], 0, 0, 0);
        }
    }
#pragma unroll
    for (int mi = 0; mi < 4; mi++) {
#pragma unroll
        for (int ni = 0; ni < 4; ni++) {
            int col = n0 + wn * 64 + ni * 16 + l16;
            float bval = bo[col];
#pragma unroll
            for (int r = 0; r < 4; r++) {
                size_t idx = (size_t)(m0 + wm * 64 + mi * 16 + quad * 4 + r) * H_ + col;
                y[idx] = acc[mi][ni][r] + bval + x[idx];
            }
        }
    }
}

// ---------------- Flash attention (causal), paired q-tiles -----------------
// grid (16 pairs, NH, B): pair p handles q-tiles p and 31-p -> 33 steps/wg.
__global__ __launch_bounds__(256) void attn_kernel(
    const unsigned short* __restrict__ qb, const unsigned short* __restrict__ kb,
    const unsigned short* __restrict__ vT, unsigned short* __restrict__ ctxb) {
    __shared__ __align__(16) unsigned short Ks[64 * 72];
    __shared__ __align__(16) unsigned short Vt[64 * 72];   // V^T tile: [d][key]
    __shared__ __align__(16) unsigned short Ps[64 * 72];   // per-wave 16-row chunks
    const int b = blockIdx.z, h = blockIdx.y, p = blockIdx.x;
    const int t = threadIdx.x, lane = t & 63, wid = t >> 6;
    const int quad = lane >> 4, l16 = lane & 15;
    const int sr = t >> 2, sc = (t & 3) * 16;
    const size_t headoff = (size_t)h * HD_;
    const unsigned short* vtb = vT + ((size_t)(b * NH_ + h) * HD_) * S_;  // [d][s]

    for (int half = 0; half < 2; half++) {
        const int qt = half ? (31 - p) : p;
        const int q0 = qt * 64;
        // Q fragments for this wave's 16 rows
        const size_t qrow = (size_t)(b * S_ + q0 + wid * 16 + l16);
        bf16x8 qf0 = *(const bf16x8*)(qb + qrow * H_ + headoff + quad * 8);
        bf16x8 qf1 = *(const bf16x8*)(qb + qrow * H_ + headoff + 32 + quad * 8);

        float m_r[4], l_r[4];
        f32x4 o_acc[4] = {};
#pragma unroll
        for (int r = 0; r < 4; r++) { m_r[r] = -INFINITY; l_r[r] = 0.f; }

        const int nsteps = qt + 1;
        for (int s = 0; s < nsteps; s++) {
            const int k0 = s * 64;
            __syncthreads();   // previous step's LDS readers done
            // stage K tile [key][d] and V^T tile [d][key], both vectorized
            us8 kv0 = *(const us8*)(kb  + (size_t)(b * S_ + k0 + sr) * H_ + headoff + sc);
            us8 kv1 = *(const us8*)(kb  + (size_t)(b * S_ + k0 + sr) * H_ + headoff + sc + 8);
            us8 vv0 = *(const us8*)(vtb + (size_t)sr * S_ + k0 + sc);
            us8 vv1 = *(const us8*)(vtb + (size_t)sr * S_ + k0 + sc + 8);
            *(us8*)&Ks[sr * 72 + sc]     = kv0;  *(us8*)&Ks[sr * 72 + sc + 8] = kv1;
            *(us8*)&Vt[sr * 72 + sc]     = vv0;  *(us8*)&Vt[sr * 72 + sc + 8] = vv1;
            __syncthreads();

            // S = Q K^T  (16x64 per wave)
            f32x4 sacc[4] = {};
#pragma unroll
            for (int kk = 0; kk < 64; kk += 32) {
                bf16x8 af = (kk == 0) ? qf0 : qf1;
#pragma unroll
                for (int nt = 0; nt < 4; nt++) {
                    bf16x8 bf = *(const bf16x8*)&Ks[(nt * 16 + l16) * 72 + kk + quad * 8];
                    sacc[nt] = __builtin_amdgcn_mfma_f32_16x16x32_bf16(af, bf, sacc[nt], 0, 0, 0);
                }
            }
            // scale + causal mask (only diagonal tile partial)
            const bool diag = (k0 == q0);
            float sv[4][4];
#pragma unroll
            for (int nt = 0; nt < 4; nt++) {
                int n = nt * 16 + l16;
#pragma unroll
                for (int r = 0; r < 4; r++) {
                    float v = sacc[nt][r] * 0.125f;        // 1/sqrt(64)
                    int qidx = wid * 16 + quad * 4 + r;
                    if (diag && n > qidx) v = -1e30f;
                    sv[nt][r] = v;
                }
            }
            // online softmax (rows across 16-lane groups)
#pragma unroll
            for (int r = 0; r < 4; r++) {
                float mx = fmaxf(fmaxf(sv[0][r], sv[1][r]), fmaxf(sv[2][r], sv[3][r]));
                mx = fmaxf(mx, __shfl_xor(mx, 1));
                mx = fmaxf(mx, __shfl_xor(mx, 2));
                mx = fmaxf(mx, __shfl_xor(mx, 4));
                mx = fmaxf(mx, __shfl_xor(mx, 8));
                float m_new = fmaxf(m_r[r], mx);
                float alpha = __expf(m_r[r] - m_new);
                float ssum = 0.f;
#pragma unroll
                for (int nt = 0; nt < 4; nt++) {
                    float pp = __expf(sv[nt][r] - m_new);
                    sv[nt][r] = pp;
                    ssum += pp;
                }
                ssum += __shfl_xor(ssum, 1);
                ssum += __shfl_xor(ssum, 2);
                ssum += __shfl_xor(ssum, 4);
                ssum += __shfl_xor(ssum, 8);
                l_r[r] = l_r[r] * alpha + ssum;
                m_r[r] = m_new;
#pragma unroll
                for (int dt = 0; dt < 4; dt++) o_acc[dt][r] *= alpha;
            }
            // P: C-layout -> A-layout via LDS (per-wave private rows)
#pragma unroll
            for (int nt = 0; nt < 4; nt++)
#pragma unroll
                for (int r = 0; r < 4; r++)
                    Ps[(wid * 16 + quad * 4 + r) * 72 + nt * 16 + l16] = f2bf(sv[nt][r]);
            __threadfence_block();   // order same-wave LDS write->read
            // O += P V
#pragma unroll
            for (int kk = 0; kk < 64; kk += 32) {
                bf16x8 pf = *(const bf16x8*)&Ps[(wid * 16 + l16) * 72 + kk + quad * 8];
#pragma unroll
                for (int dt = 0; dt < 4; dt++) {
                    bf16x8 vf = *(const bf16x8*)&Vt[(dt * 16 + l16) * 72 + kk + quad * 8];
                    o_acc[dt] = __builtin_amdgcn_mfma_f32_16x16x32_bf16(pf, vf, o_acc[dt], 0, 0, 0);
                }
            }
        }
        // normalize + store ctx
#pragma unroll
        for (int r = 0; r < 4; r++) {
            float inv = 1.0f / l_r[r];
            size_t row = (size_t)(b * S_ + q0 + wid * 16 + quad * 4 + r);
#pragma unroll
            for (int dt = 0; dt < 4; dt++)
                ctxb[row * H_ + headoff + dt * 16 + l16] = f2bf(o_acc[dt][r] * inv);
        }
    }
}

// ---------------- LayerNorm (1 block per row) ----------------
__global__ __launch_bounds__(256) void ln_kernel(
    const float* __restrict__ y, const float* __restrict__ g,
    const float* __restrict__ bta, float* __restrict__ out) {
    __shared__ float red[8];
    const int row = blockIdx.x, t = threadIdx.x;
    fl4 v = *(const fl4*)(y + (size_t)row * H_ + t * 4);
    float s  = v.x + v.y + v.z + v.w;
    float sq = v.x * v.x + v.y * v.y + v.z * v.z + v.w * v.w;
    for (int m = 1; m < 64; m <<= 1) { s += __shfl_xor(s, m); sq += __shfl_xor(sq, m); }
    const int wid = t >> 6, lane = t & 63;
    if (lane == 0) { red[wid * 2] = s; red[wid * 2 + 1] = sq; }
    __syncthreads();
    s  = red[0] + red[2] + red[4] + red[6];
    sq = red[1] + red[3] + red[5] + red[7];
    float mu   = s * (1.0f / H_);
    float var  = sq * (1.0f / H_) - mu * mu;
    float rstd = rsqrtf(fmaxf(var, 0.f) + 1e-12f);
    fl4 gg = *(const fl4*)(g + t * 4);
    fl4 bb = *(const fl4*)(bta + t * 4);
    fl4 o;
    o.x = (v.x - mu) * rstd * gg.x + bb.x;
    o.y = (v.y - mu) * rstd * gg.y + bb.y;
    o.z = (v.z - mu) * rstd * gg.z + bb.z;
    o.w = (v.w - mu) * rstd * gg.w + bb.w;
    *(fl4*)(out + (size_t)row * H_ + t * 4) = o;
}

extern "C" void kernel_launch(void* const* d_in, const int* in_sizes, int n_in,
                              void* d_out, int out_size, void* d_ws, size_t ws_size,
                              hipStream_t stream) {
    const float* x  = (const float*)d_in[0];
    const float* Wq = (const float*)d_in[1];
    const float* bq = (const float*)d_in[2];
    const float* Wk = (const float*)d_in[3];
    const float* bk = (const float*)d_in[4];
    const float* Wv = (const float*)d_in[5];
    const float* bv = (const float*)d_in[6];
    const float* Wo = (const float*)d_in[7];
    const float* bo = (const float*)d_in[8];
    const float* lg = (const float*)d_in[9];
    const float* lb = (const float*)d_in[10];
    float* out = (float*)d_out;

    const size_t MEG = 1024u * 1024u;
    unsigned short* ws16 = (unsigned short*)d_ws;
    unsigned short* xb   = ws16;                  // 4M bf16
    unsigned short* wb   = ws16 + 4 * MEG;        // 4x1M bf16 (Wq,Wk,Wv,Wo)
    unsigned short* qb   = ws16 + 8 * MEG;        // 4M bf16
    unsigned short* kb   = ws16 + 12 * MEG;
    unsigned short* vT   = ws16 + 16 * MEG;       // transposed V [b,h,d,s]
    unsigned short* ctxb = ws16 + 20 * MEG;
    float* y = (float*)(ws16 + 24 * MEG);         // 4M fp32; total 64 MB

    cast_kernel<<<8192, 256, 0, stream>>>(x, Wq, Wk, Wv, Wo, xb, wb);
    gemm_qkv<<<dim3(32, 8, 3), 256, 0, stream>>>(xb, wb, bq, bk, bv, qb, kb, vT);
    attn_kernel<<<dim3(16, 16, 2), 256, 0, stream>>>(qb, kb, vT, ctxb);
    gemm_out<<<dim3(32, 8), 256, 0, stream>>>(ctxb, wb + 3 * MEG, bo, x, y);
    ln_kernel<<<4096, 256, 0, stream>>>(y, lg, lb, out);
}